// Round 4
// baseline (228.825 us; speedup 1.0000x reference)
//
#include <hip/hip_runtime.h>

// MLPNodeLink: out[i,j] = relu(relu(relu([V1_i|V2_j]@W1+b1)@W2+b2)@W3+b3)
// h1[i,j] = relu(A[i] + B[j]), A=V1@W1[:128]+b1, B=V2@W1[128:]
// Layer-2 (137 GFLOP) via bf16 MFMA; layer-3 fused into epilogue.
// Round 4: OUTPUT IS FLOAT32 (reference returns f32; npz sizes confirm).
// Identical to round 3 except out is float* and stores are plain floats.

typedef short bf16x8 __attribute__((ext_vector_type(8)));
typedef float f32x4 __attribute__((ext_vector_type(4)));

#define NROW 512
#define FDIM 128
#define HDIM 512

__device__ __forceinline__ unsigned short f2bf(float x) {
  unsigned int u = __builtin_bit_cast(unsigned int, x);
  u += 0x7fffu + ((u >> 16) & 1u);
  return (unsigned short)(u >> 16);
}

// ---- prep_ab: A[i][h] = V1[i]@W1[:128] + b1 ; B[j][h] = V2[j]@W1[128:] ----
__global__ __launch_bounds__(256) void prep_ab(
    const float* __restrict__ V1, const float* __restrict__ V2,
    const float* __restrict__ W1, const float* __restrict__ b1,
    float* __restrict__ Ap, float* __restrict__ Bp) {
  __shared__ float sv[4 * FDIM];
  const int b = blockIdx.x;
  const int t = threadIdx.x;
  const bool isB = b >= 128;
  const int r0 = (b & 127) * 4;
  const float* V = isB ? V2 : V1;
  const float* W = W1 + (isB ? FDIM * HDIM : 0);
  for (int idx = t; idx < 4 * FDIM; idx += 256) sv[idx] = V[r0 * FDIM + idx];
  __syncthreads();
  float s[4][2] = {};
  for (int k = 0; k < FDIM; ++k) {
    const float w0 = W[k * HDIM + t];
    const float w1 = W[k * HDIM + t + 256];
#pragma unroll
    for (int r = 0; r < 4; ++r) {
      const float v = sv[r * FDIM + k];
      s[r][0] += v * w0;
      s[r][1] += v * w1;
    }
  }
  float* O = isB ? Bp : Ap;
  const float bb0 = isB ? 0.f : b1[t];
  const float bb1 = isB ? 0.f : b1[t + 256];
#pragma unroll
  for (int r = 0; r < 4; ++r) {
    O[(r0 + r) * HDIM + t] = s[r][0] + bb0;
    O[(r0 + r) * HDIM + t + 256] = s[r][1] + bb1;
  }
}

// ---- prep_w2: bf16 W2^T, tiled per BK=32 k-tile for coalesced staging ----
// Chunk o (16B, 32768 total): kt=o>>11, n=(o>>2)&511, s=o&3 holds
// W2[kt*32 + s*8 + e][n] for e=0..7.
__global__ __launch_bounds__(256) void prep_w2(const float* __restrict__ W2,
                                               unsigned short* __restrict__ W2T) {
  const int o = blockIdx.x * 256 + threadIdx.x;  // 128 blocks * 256 = 32768
  const int kt = o >> 11;
  const int n = (o >> 2) & 511;
  const int s = o & 3;
  const int kb = kt * 32 + s * 8;
  unsigned int u[4];
#pragma unroll
  for (int e2 = 0; e2 < 4; ++e2) {
    const unsigned short lo = f2bf(W2[(kb + 2 * e2) * HDIM + n]);
    const unsigned short hi = f2bf(W2[(kb + 2 * e2 + 1) * HDIM + n]);
    u[e2] = (unsigned)lo | ((unsigned)hi << 16);
  }
  *(uint4*)(W2T + (size_t)o * 8) = make_uint4(u[0], u[1], u[2], u[3]);
}

// ---- main: 64 pair-rows (one i, 64 j's) x full 512 cols per block ----
// 8 waves; each wave owns 64x64 (4 mt x 4 nt fragments). BK=32, 16 k-tiles.
__global__ __launch_bounds__(512, 4) void mlp_main(
    const float* __restrict__ Ap, const float* __restrict__ Bp,
    const unsigned short* __restrict__ W2T, const float* __restrict__ b2,
    const float* __restrict__ W3, const float* __restrict__ b3,
    float* __restrict__ out) {
  __shared__ unsigned short sB[512 * 40];  // W2 tile: 512 n-rows, 80B stride (64B data+pad)
  __shared__ unsigned short sA[64 * 40];   // h1 tile: 64 rows, 80B stride
  __shared__ float sP[8][64][2];           // layer-3 per-wave partials

  const int tid = threadIdx.x;
  const int wave = tid >> 6;
  const int lane = tid & 63;
  const int lane15 = lane & 15;
  const int kgrp = lane >> 4;  // 0..3

  const int m0 = blockIdx.x * 64;
  const int i = m0 >> 9;
  const int j0 = m0 & 511;

  const int rA = tid >> 3;  // 0..63  (sA staging row)
  const int qA = tid & 7;   // 0..7   (k-quad, 4 elems)
  const float* ApRow = Ap + i * HDIM;
  const float* BpRow = Bp + (j0 + rA) * HDIM;

  f32x4 acc[4][4];
#pragma unroll
  for (int a = 0; a < 4; ++a)
#pragma unroll
    for (int bq = 0; bq < 4; ++bq) acc[a][bq] = (f32x4){0.f, 0.f, 0.f, 0.f};

  for (int kt = 0; kt < 16; ++kt) {
    // stage W2 k-tile -> sB (coalesced global, padded LDS rows)
    {
      const uint4* src = (const uint4*)(W2T + (kt << 14));
#pragma unroll
      for (int it = 0; it < 4; ++it) {
        const int c = (it << 9) + tid;  // 0..2047
        const int n = c >> 2;
        const int s = c & 3;
        const uint4 v = src[c];
        *(uint4*)((char*)sB + n * 80 + (s << 4)) = v;
      }
    }
    // stage h1 k-slice -> sA: relu(A[i][k] + B[j][k]) in bf16 (4 elems/thread)
    {
      const int kk = (kt << 5) + (qA << 2);
      const float4 a = *(const float4*)(ApRow + kk);
      const float4 g = *(const float4*)(BpRow + kk);
      const unsigned int u0 =
          (unsigned)f2bf(fmaxf(a.x + g.x, 0.f)) | ((unsigned)f2bf(fmaxf(a.y + g.y, 0.f)) << 16);
      const unsigned int u1 =
          (unsigned)f2bf(fmaxf(a.z + g.z, 0.f)) | ((unsigned)f2bf(fmaxf(a.w + g.w, 0.f)) << 16);
      *(uint2*)((char*)sA + rA * 80 + (qA << 3)) = make_uint2(u0, u1);
    }
    __syncthreads();
    // MFMA: one K=32 step per tile; 4 mt x 4 nt fragments per wave
    bf16x8 af[4];
#pragma unroll
    for (int mt = 0; mt < 4; ++mt)
      af[mt] = *(const bf16x8*)((const char*)sA + (mt * 16 + lane15) * 80 + (kgrp << 4));
#pragma unroll
    for (int nt = 0; nt < 4; ++nt) {
      const int n = (wave << 6) + (nt << 4) + lane15;
      const bf16x8 bv = *(const bf16x8*)((const char*)sB + n * 80 + (kgrp << 4));
#pragma unroll
      for (int mt = 0; mt < 4; ++mt)
        acc[mt][nt] = __builtin_amdgcn_mfma_f32_16x16x32_bf16(af[mt], bv, acc[mt][nt], 0, 0, 0);
    }
    __syncthreads();
  }

  // epilogue: h2 = relu(acc + b2); layer-3 partials; reduce; store f32
  float w30[4], w31[4], bbv[4];
#pragma unroll
  for (int nt = 0; nt < 4; ++nt) {
    const int n = (wave << 6) + (nt << 4) + lane15;
    w30[nt] = W3[2 * n];
    w31[nt] = W3[2 * n + 1];
    bbv[nt] = b2[n];
  }
#pragma unroll
  for (int mt = 0; mt < 4; ++mt) {
    float p[4][2] = {};
#pragma unroll
    for (int nt = 0; nt < 4; ++nt)
#pragma unroll
      for (int q = 0; q < 4; ++q) {
        const float h = fmaxf(acc[mt][nt][q] + bbv[nt], 0.f);
        p[q][0] += h * w30[nt];
        p[q][1] += h * w31[nt];
      }
#pragma unroll
    for (int d = 1; d < 16; d <<= 1)
#pragma unroll
      for (int q = 0; q < 4; ++q) {
        p[q][0] += __shfl_xor(p[q][0], d, 64);
        p[q][1] += __shfl_xor(p[q][1], d, 64);
      }
    if (lane15 == 0) {
#pragma unroll
      for (int q = 0; q < 4; ++q) {
        sP[wave][mt * 16 + kgrp * 4 + q][0] = p[q][0];
        sP[wave][mt * 16 + kgrp * 4 + q][1] = p[q][1];
      }
    }
  }
  __syncthreads();
  if (tid < 128) {
    const int r = tid >> 1;
    const int c = tid & 1;
    float v = b3[c];
#pragma unroll
    for (int w = 0; w < 8; ++w) v += sP[w][r][c];
    out[((m0 + r) << 1) + c] = fmaxf(v, 0.f);
  }
}

extern "C" void kernel_launch(void* const* d_in, const int* in_sizes, int n_in,
                              void* d_out, int out_size, void* d_ws, size_t ws_size,
                              hipStream_t stream) {
  const float* V1 = (const float*)d_in[0];
  const float* V2 = (const float*)d_in[1];
  const float* W1 = (const float*)d_in[2];
  const float* b1 = (const float*)d_in[3];
  const float* W2 = (const float*)d_in[4];
  const float* b2 = (const float*)d_in[5];
  const float* W3 = (const float*)d_in[6];
  const float* b3 = (const float*)d_in[7];

  // ws layout: Ap (1MB f32) | Bp (1MB f32) | W2T (512KB bf16 tiled)
  float* Ap = (float*)d_ws;
  float* Bp = Ap + NROW * HDIM;
  unsigned short* W2T = (unsigned short*)(Bp + NROW * HDIM);

  prep_ab<<<256, 256, 0, stream>>>(V1, V2, W1, b1, Ap, Bp);
  prep_w2<<<128, 256, 0, stream>>>(W2, W2T);
  mlp_main<<<4096, 512, 0, stream>>>(Ap, Bp, W2T, b2, W3, b3, (float*)d_out);
}

// Round 5
// 167.123 us; speedup vs baseline: 1.3692x; 1.3692x over previous
//
#include <hip/hip_runtime.h>

// MLPNodeLink: out[i,j] = relu(relu(relu([V1_i|V2_j]@W1+b1)@W2+b2)@W3+b3)
// h1[i,j] = relu(A[i] + B[j]), A=V1@W1[:128]+b1, B=V2@W1[128:]
// Round 5: barrier-free K-loop. h1 (128 rows x 512 k, bf16, XOR-swizzled)
// computed once into 128KB dynamic LDS; W2 fragments read DIRECTLY from L2
// (no intra-block W2 reuse with BN=512, so LDS staging of W2 was pure cost),
// register ping-pong prefetch one K-tile ahead. Layer-3 fused in epilogue.

typedef short bf16x8 __attribute__((ext_vector_type(8)));
typedef float f32x4 __attribute__((ext_vector_type(4)));

#define NROW 512
#define FDIM 128
#define HDIM 512

__device__ __forceinline__ unsigned short f2bf(float x) {
  unsigned int u = __builtin_bit_cast(unsigned int, x);
  u += 0x7fffu + ((u >> 16) & 1u);
  return (unsigned short)(u >> 16);
}
__device__ __forceinline__ unsigned int pk2(float x, float y) {
  return (unsigned)f2bf(x) | ((unsigned)f2bf(y) << 16);
}

// ---- prep_ab: A[i][h] = V1[i]@W1[:128] + b1 ; B[j][h] = V2[j]@W1[128:] ----
__global__ __launch_bounds__(256) void prep_ab(
    const float* __restrict__ V1, const float* __restrict__ V2,
    const float* __restrict__ W1, const float* __restrict__ b1,
    float* __restrict__ Ap, float* __restrict__ Bp) {
  __shared__ float sv[4 * FDIM];
  const int b = blockIdx.x;
  const int t = threadIdx.x;
  const bool isB = b >= 128;
  const int r0 = (b & 127) * 4;
  const float* V = isB ? V2 : V1;
  const float* W = W1 + (isB ? FDIM * HDIM : 0);
  for (int idx = t; idx < 4 * FDIM; idx += 256) sv[idx] = V[r0 * FDIM + idx];
  __syncthreads();
  float s[4][2] = {};
  for (int k = 0; k < FDIM; ++k) {
    const float w0 = W[k * HDIM + t];
    const float w1 = W[k * HDIM + t + 256];
#pragma unroll
    for (int r = 0; r < 4; ++r) {
      const float v = sv[r * FDIM + k];
      s[r][0] += v * w0;
      s[r][1] += v * w1;
    }
  }
  float* O = isB ? Bp : Ap;
  const float bb0 = isB ? 0.f : b1[t];
  const float bb1 = isB ? 0.f : b1[t + 256];
#pragma unroll
  for (int r = 0; r < 4; ++r) {
    O[(r0 + r) * HDIM + t] = s[r][0] + bb0;
    O[(r0 + r) * HDIM + t + 256] = s[r][1] + bb1;
  }
}

// ---- prep_w2: bf16 W2^T tiled as [kt(8)][slot(8)][n(512)] 16B chunks ----
// Chunk o holds W2[kt*64 + slot*8 + e][n], e=0..7.  A quarter-wave (fixed
// slot, consecutive n) then loads 256B contiguous from L2 in the main loop.
__global__ __launch_bounds__(256) void prep_w2(const float* __restrict__ W2,
                                               unsigned short* __restrict__ W2T) {
  const int o = blockIdx.x * 256 + threadIdx.x;  // 128*256 = 32768 chunks
  const int kt = o >> 12;
  const int s = (o >> 9) & 7;
  const int n = o & 511;
  const int kb = kt * 64 + s * 8;
  unsigned int u[4];
#pragma unroll
  for (int e2 = 0; e2 < 4; ++e2) {
    const unsigned short lo = f2bf(W2[(kb + 2 * e2) * HDIM + n]);
    const unsigned short hi = f2bf(W2[(kb + 2 * e2 + 1) * HDIM + n]);
    u[e2] = (unsigned)lo | ((unsigned)hi << 16);
  }
  *(uint4*)(W2T + (size_t)o * 8) = make_uint4(u[0], u[1], u[2], u[3]);
}

// ---- main: 128 pair-rows (one i, 128 j's) x full 512 cols per block ----
// 8 waves; wave owns all 128 rows x 64 cols (8 mt x 4 nt). K = 8 tiles of 64.
// LDS: sA = h1[128][512] bf16, chunk-XOR-swizzled (128KB) | sP (8KB).
__global__ __launch_bounds__(512, 2) void mlp_main(
    const float* __restrict__ Ap, const float* __restrict__ Bp,
    const unsigned short* __restrict__ W2T, const float* __restrict__ b2,
    const float* __restrict__ W3, const float* __restrict__ b3,
    float* __restrict__ out) {
  extern __shared__ char smem[];
  char* sA = smem;                         // 128 rows * 1024B, chunk c at byte (c^(row&7))*16
  float* sP = (float*)(smem + 131072);     // [8][128][2]

  const int tid = threadIdx.x;
  const int wave = tid >> 6;
  const int lane = tid & 63;
  const int lane15 = lane & 15;
  const int kgrp = lane >> 4;  // 0..3
  const int sw = lane15 & 7;   // row&7 for this lane's A-frag rows

  const int m0 = blockIdx.x * 128;
  const int i = m0 >> 9;
  const int j0 = m0 & 511;

  // ---- fill phase: h1 tile -> sA ----
  {
    const int c = tid & 63;        // 16B chunk within row (8 k-elems)
    const int rsub = tid >> 6;     // 0..7
    const float4 a0 = *(const float4*)(Ap + i * HDIM + c * 8);
    const float4 a1 = *(const float4*)(Ap + i * HDIM + c * 8 + 4);
#pragma unroll
    for (int it = 0; it < 16; ++it) {
      const int row = it * 8 + rsub;
      const float4 g0 = *(const float4*)(Bp + (size_t)(j0 + row) * HDIM + c * 8);
      const float4 g1 = *(const float4*)(Bp + (size_t)(j0 + row) * HDIM + c * 8 + 4);
      const uint4 v = make_uint4(
          pk2(fmaxf(a0.x + g0.x, 0.f), fmaxf(a0.y + g0.y, 0.f)),
          pk2(fmaxf(a0.z + g0.z, 0.f), fmaxf(a0.w + g0.w, 0.f)),
          pk2(fmaxf(a1.x + g1.x, 0.f), fmaxf(a1.y + g1.y, 0.f)),
          pk2(fmaxf(a1.z + g1.z, 0.f), fmaxf(a1.w + g1.w, 0.f)));
      *(uint4*)(sA + row * 1024 + ((c ^ (row & 7)) << 4)) = v;
    }
  }
  __syncthreads();

  // ---- barrier-free K-loop ----
  f32x4 acc[8][4];
#pragma unroll
  for (int mt = 0; mt < 8; ++mt)
#pragma unroll
    for (int nt = 0; nt < 4; ++nt) acc[mt][nt] = (f32x4){0.f, 0.f, 0.f, 0.f};

  // B-frag base: chunk index = kt*4096 + (ks*4+kgrp)*512 + wave*64 + nt*16 + lane15
  const char* bbase = (const char*)W2T + (((kgrp << 9) + (wave << 6) + lane15) << 4);

  bf16x8 bf[2][2][4];  // [ping-pong][ks][nt]
#pragma unroll
  for (int ks = 0; ks < 2; ++ks)
#pragma unroll
    for (int nt = 0; nt < 4; ++nt)
      bf[0][ks][nt] = *(const bf16x8*)(bbase + (ks << 15) + (nt << 8));

#pragma unroll
  for (int kt = 0; kt < 8; ++kt) {
    const int cur = kt & 1;
    if (kt < 7) {
      const char* p = bbase + ((kt + 1) << 16);
#pragma unroll
      for (int ks = 0; ks < 2; ++ks)
#pragma unroll
        for (int nt = 0; nt < 4; ++nt)
          bf[cur ^ 1][ks][nt] = *(const bf16x8*)(p + (ks << 15) + (nt << 8));
    }
#pragma unroll
    for (int ks = 0; ks < 2; ++ks) {
      const int csel = ((ks << 2) | kgrp) ^ sw;  // swizzled low-3+ks bits
      bf16x8 af[8];
#pragma unroll
      for (int mt = 0; mt < 8; ++mt) {
        const int row = mt * 16 + lane15;
        af[mt] = *(const bf16x8*)(sA + row * 1024 + (((kt << 3) | csel) << 4));
      }
#pragma unroll
      for (int nt = 0; nt < 4; ++nt)
#pragma unroll
        for (int mt = 0; mt < 8; ++mt)
          acc[mt][nt] =
              __builtin_amdgcn_mfma_f32_16x16x32_bf16(af[mt], bf[cur][ks][nt], acc[mt][nt], 0, 0, 0);
    }
  }

  // ---- epilogue: h2 = relu(acc + b2); layer-3 partials; reduce; store ----
  float w30[4], w31[4], bbv[4];
#pragma unroll
  for (int nt = 0; nt < 4; ++nt) {
    const int n = (wave << 6) + (nt << 4) + lane15;
    w30[nt] = W3[2 * n];
    w31[nt] = W3[2 * n + 1];
    bbv[nt] = b2[n];
  }
#pragma unroll
  for (int mt = 0; mt < 8; ++mt) {
    float p[4][2] = {};
#pragma unroll
    for (int nt = 0; nt < 4; ++nt)
#pragma unroll
      for (int q = 0; q < 4; ++q) {
        const float h = fmaxf(acc[mt][nt][q] + bbv[nt], 0.f);
        p[q][0] += h * w30[nt];
        p[q][1] += h * w31[nt];
      }
#pragma unroll
    for (int d = 1; d < 16; d <<= 1)
#pragma unroll
      for (int q = 0; q < 4; ++q) {
        p[q][0] += __shfl_xor(p[q][0], d, 64);
        p[q][1] += __shfl_xor(p[q][1], d, 64);
      }
    if (lane15 == 0) {
#pragma unroll
      for (int q = 0; q < 4; ++q) {
        const int r = mt * 16 + kgrp * 4 + q;
        sP[(wave * 128 + r) * 2 + 0] = p[q][0];
        sP[(wave * 128 + r) * 2 + 1] = p[q][1];
      }
    }
  }
  __syncthreads();
  if (tid < 256) {
    const int r = tid >> 1;
    const int c = tid & 1;
    float v = b3[c];
#pragma unroll
    for (int w = 0; w < 8; ++w) v += sP[(w * 128 + r) * 2 + c];
    out[((m0 + r) << 1) + c] = fmaxf(v, 0.f);
  }
}

extern "C" void kernel_launch(void* const* d_in, const int* in_sizes, int n_in,
                              void* d_out, int out_size, void* d_ws, size_t ws_size,
                              hipStream_t stream) {
  const float* V1 = (const float*)d_in[0];
  const float* V2 = (const float*)d_in[1];
  const float* W1 = (const float*)d_in[2];
  const float* b1 = (const float*)d_in[3];
  const float* W2 = (const float*)d_in[4];
  const float* b2 = (const float*)d_in[5];
  const float* W3 = (const float*)d_in[6];
  const float* b3 = (const float*)d_in[7];

  // ws layout: Ap (1MB f32) | Bp (1MB f32) | W2T (512KB bf16 tiled)
  float* Ap = (float*)d_ws;
  float* Bp = Ap + NROW * HDIM;
  unsigned short* W2T = (unsigned short*)(Bp + NROW * HDIM);

  const int smem_bytes = 131072 + 8 * 128 * 2 * 4;  // sA + sP = 139264
  (void)hipFuncSetAttribute((const void*)mlp_main,
                            hipFuncAttributeMaxDynamicSharedMemorySize, smem_bytes);

  prep_ab<<<256, 256, 0, stream>>>(V1, V2, W1, b1, Ap, Bp);
  prep_w2<<<128, 256, 0, stream>>>(W2, W2T);
  mlp_main<<<2048, 512, smem_bytes, stream>>>(Ap, Bp, W2T, b2, W3, b3, (float*)d_out);
}